// Round 9
// baseline (933.931 us; speedup 1.0000x reference)
//
#include <hip/hip_runtime.h>
#include <hip/hip_bf16.h>

typedef float f32x4 __attribute__((ext_vector_type(4)));
typedef __bf16 bf16x8 __attribute__((ext_vector_type(8)));

#define B_SZ 2048
#define IN_SZ 2048
#define H_SZ 1024
#define G_SZ (4 * H_SZ)   // 4096
#define T_STEPS 15
#define INIT_ST 0.01f

__device__ __forceinline__ float sigmoid_f(float x) { return 1.0f / (1.0f + __expf(-x)); }
__device__ __forceinline__ float tanh_f(float x)    { return 1.0f - 2.0f / (__expf(2.0f * x) + 1.0f); }

// fp32x8 -> bf16 hi + bf16 lo (Markidis split)
__device__ __forceinline__ void split8(f32x4 v0, f32x4 v1, bf16x8* h, bf16x8* l) {
  bf16x8 hv, lv;
  #pragma unroll
  for (int j = 0; j < 4; ++j) {
    float f = v0[j];
    __bf16 hb = (__bf16)f;
    hv[j] = hb;
    lv[j] = (__bf16)(f - (float)hb);
  }
  #pragma unroll
  for (int j = 0; j < 4; ++j) {
    float f = v1[j];
    __bf16 hb = (__bf16)f;
    hv[4 + j] = hb;
    lv[4 + j] = (__bf16)(f - (float)hb);
  }
  *h = hv;
  *l = lv;
}

// fp32x8 -> bf16 (round-to-nearest, hi only)
__device__ __forceinline__ bf16x8 cvt8(f32x4 v0, f32x4 v1) {
  bf16x8 hv;
  #pragma unroll
  for (int j = 0; j < 4; ++j) hv[j] = (__bf16)v0[j];
  #pragma unroll
  for (int j = 0; j < 4; ++j) hv[4 + j] = (__bf16)v1[j];
  return hv;
}

// async global -> LDS, 16 bytes/lane; src per-lane, dest wave-uniform base.
__device__ __forceinline__ void gl16(const bf16x8* src, bf16x8* lds_base_uniform) {
  __builtin_amdgcn_global_load_lds(
      (const __attribute__((address_space(1))) void*)src,
      (__attribute__((address_space(3))) void*)lds_base_uniform, 16, 0, 0);
}

// Swizzle v2: chunk(row, kc) = row*4 + (kc ^ ((row>>1)&3)).
// Within a 16-lane frag-read group (kc const, row cycling), chunk%8 covers all
// 8 slots -> 2 lanes/16B-slot = bank-conflict-free (v1's kc^(row&3) gave 4-way).

// ---------------------------------------------------------------------------
// Repack W_hh (fp32 [4096][1024]) -> bf16 chunks in B-tile order, swizzle v2:
//   cid = ((nt*32 + ks)*1024 + s);  s: row = s>>2 (0..255), kc = (s&3)^((row>>1)&3)
//   row: gate = row>>6, col = row&63
// ---------------------------------------------------------------------------
__global__ __launch_bounds__(256)
void repack_whh(const float* __restrict__ Whh, bf16x8* __restrict__ Wh)
{
  int cid = blockIdx.x * 256 + threadIdx.x;     // 0 .. 524287
  int s    = cid & 1023;
  int rest = cid >> 10;       // nt*32 + ks
  int ks   = rest & 31;
  int nt   = rest >> 5;       // 0..15
  int row  = s >> 2;          // 0..255
  int kc   = (s & 3) ^ ((row >> 1) & 3);
  int gate = row >> 6, col = row & 63;
  const float* src = Whh + (size_t)(gate * H_SZ + nt * 64 + col) * H_SZ + ks * 32 + kc * 8;
  Wh[cid] = cvt8(*(const f32x4*)src, *(const f32x4*)(src + 4));
}

// h0 = 0.01 everywhere, pre-split (layout-independent since constant)
__global__ __launch_bounds__(256)
void init_h0(bf16x8* __restrict__ hh, bf16x8* __restrict__ hl)
{
  int cid = blockIdx.x * 256 + threadIdx.x;     // 0 .. 262143
  __bf16 hi = (__bf16)INIT_ST;
  __bf16 lo = (__bf16)(INIT_ST - (float)hi);
  bf16x8 h, l;
  #pragma unroll
  for (int j = 0; j < 8; ++j) { h[j] = hi; l[j] = lo; }
  hh[cid] = h;
  hl[cid] = l;
}

// ---------------------------------------------------------------------------
// xg = x @ W_ih^T + b_ih + b_hh   (3-term split; swizzle v2; 4 blocks/CU)
// ---------------------------------------------------------------------------
__global__ __launch_bounds__(256, 4)
void xg_gemm(const float* __restrict__ x, const float* __restrict__ Wih,
             const float* __restrict__ bih, const float* __restrict__ bhh,
             float* __restrict__ xg)
{
  __shared__ bf16x8 Ah[128 * 4], Al[128 * 4], Bh[128 * 4], Bl[128 * 4];
  const int tid  = threadIdx.x;
  const int lane = tid & 63;
  const int wv   = tid >> 6;
  const int wm   = wv >> 1, wn = wv & 1;
  const int bm   = blockIdx.y * 128;
  const int bn   = blockIdx.x * 128;

  f32x4 acc[4][4] = {};

  for (int k0 = 0; k0 < IN_SZ; k0 += 32) {
    #pragma unroll
    for (int c = 0; c < 2; ++c) {
      int cid = tid + c * 256;
      int row = cid >> 2, kc = cid & 3;
      int idx = row * 4 + (kc ^ ((row >> 1) & 3));
      const float* srcA = x + (size_t)(bm + row) * IN_SZ + k0 + kc * 8;
      split8(*(const f32x4*)srcA, *(const f32x4*)(srcA + 4), &Ah[idx], &Al[idx]);
      const float* srcB = Wih + (size_t)(bn + row) * IN_SZ + k0 + kc * 8;
      split8(*(const f32x4*)srcB, *(const f32x4*)(srcB + 4), &Bh[idx], &Bl[idx]);
    }
    __syncthreads();

    const int kc = lane >> 4;
    bf16x8 ah[4], al[4], bh[4], bl[4];
    #pragma unroll
    for (int i = 0; i < 4; ++i) {
      int ra = wm * 64 + i * 16 + (lane & 15);
      int ia = ra * 4 + (kc ^ ((ra >> 1) & 3));
      ah[i] = Ah[ia]; al[i] = Al[ia];
      int rb = wn * 64 + i * 16 + (lane & 15);
      int ib = rb * 4 + (kc ^ ((rb >> 1) & 3));
      bh[i] = Bh[ib]; bl[i] = Bl[ib];
    }
    #pragma unroll
    for (int i = 0; i < 4; ++i)
      #pragma unroll
      for (int j = 0; j < 4; ++j) {
        acc[i][j] = __builtin_amdgcn_mfma_f32_16x16x32_bf16(ah[i], bh[j], acc[i][j], 0, 0, 0);
        acc[i][j] = __builtin_amdgcn_mfma_f32_16x16x32_bf16(ah[i], bl[j], acc[i][j], 0, 0, 0);
        acc[i][j] = __builtin_amdgcn_mfma_f32_16x16x32_bf16(al[i], bh[j], acc[i][j], 0, 0, 0);
      }
    __syncthreads();
  }

  #pragma unroll
  for (int i = 0; i < 4; ++i) {
    int m0 = bm + wm * 64 + i * 16 + ((lane >> 4) * 4);
    #pragma unroll
    for (int j = 0; j < 4; ++j) {
      int n = bn + wn * 64 + j * 16 + (lane & 15);
      float bb = bih[n] + bhh[n];
      #pragma unroll
      for (int r = 0; r < 4; ++r)
        xg[(size_t)(m0 + r) * G_SZ + n] = acc[i][j][r] + bb;
    }
  }
}

// ---------------------------------------------------------------------------
// Fused LSTM step v4:
//   BM=128 batch x BN=256 (4 gates x 64 cols), BK=32, 256 threads = 4 waves
//   Wave grid 2M x 2N, wave tile 64 x 128 (2 gates/wave) -> LDS reads
//   64 KB/K-step/CU (was 96), 256 B/MFMA.
//   Ring-3 LDS (3 x 32 KB = 96 KB), stage 3 ahead, vmcnt(8), reg frag dbuf.
//   Swizzle v2 throughout. Math order identical -> bit-identical output.
// ---------------------------------------------------------------------------
__global__ __launch_bounds__(256, 1)
void lstm_step(const bf16x8* __restrict__ hsh,  // h_prev split hi [32mt64][32ks][256]
               const bf16x8* __restrict__ hsl,  // h_prev split lo
               const bf16x8* __restrict__ Wh,   // W_hh bf16 [16nt][32ks][1024]
               const float* __restrict__ xg,    // [2048][4096], biases folded
               float* __restrict__ cst,         // [2048][1024]
               float* __restrict__ hout,        // fp32 out slice
               bf16x8* __restrict__ hnh,        // next-step h split hi
               bf16x8* __restrict__ hnl,        // next-step h split lo
               int first)
{
  __shared__ __attribute__((aligned(16))) char smem[98304];  // 3 x 32 KB
  bf16x8* L = (bf16x8*)smem;  // per buf (2048): [A hi 512][A lo 512][B 1024]

  const int tid  = threadIdx.x;
  const int lane = tid & 63;
  const int wv   = tid >> 6;       // wave 0..3
  const int wm   = wv >> 1;        // batch half 0..1 (64 rows)
  const int wn   = wv & 1;         // gate-pair 0..1 (128 cols)

  // XCD-aware remap: 256 blocks, 32/XCD -> each XCD owns 2 nt slices (1 MB W).
  const int bid  = blockIdx.x;
  const int wgid = (bid & 7) * 32 + (bid >> 3);
  const int nt   = wgid >> 4;      // 0..15 hidden-col tile
  const int mt   = wgid & 15;      // 0..15 batch tile (128 rows)

  f32x4 acc[4][8] = {};            // [mi][nj]
  const int kc = lane >> 4;

  bf16x8 ahA[4], alA[4], bhA[8];   // frag set A
  bf16x8 ahB[4], alB[4], bhB[8];   // frag set B

#define STAGE(BUF, KS)                                                        \
  do {                                                                        \
    gl16(hsh + ((size_t)(2 * mt)     * 32 + (KS)) * 256 + tid, L + (BUF) * 2048 +        wv * 64); \
    gl16(hsh + ((size_t)(2 * mt + 1) * 32 + (KS)) * 256 + tid, L + (BUF) * 2048 + 256  + wv * 64); \
    gl16(hsl + ((size_t)(2 * mt)     * 32 + (KS)) * 256 + tid, L + (BUF) * 2048 + 512  + wv * 64); \
    gl16(hsl + ((size_t)(2 * mt + 1) * 32 + (KS)) * 256 + tid, L + (BUF) * 2048 + 768  + wv * 64); \
    const bf16x8* sb = Wh + ((size_t)nt * 32 + (KS)) * 1024;                  \
    gl16(sb + tid,       L + (BUF) * 2048 + 1024 + wv * 64);                  \
    gl16(sb + 256 + tid, L + (BUF) * 2048 + 1280 + wv * 64);                  \
    gl16(sb + 512 + tid, L + (BUF) * 2048 + 1536 + wv * 64);                  \
    gl16(sb + 768 + tid, L + (BUF) * 2048 + 1792 + wv * 64);                  \
  } while (0)

#define READF(S, BUF)                                                         \
  do {                                                                        \
    _Pragma("unroll")                                                         \
    for (int i = 0; i < 4; ++i) {                                             \
      int ra = wm * 64 + i * 16 + (lane & 15);                                \
      int ca = (BUF) * 2048 + ra * 4 + (kc ^ ((ra >> 1) & 3));                \
      ah##S[i] = L[ca];                                                       \
      al##S[i] = L[ca + 512];                                                 \
    }                                                                         \
    _Pragma("unroll")                                                         \
    for (int j = 0; j < 8; ++j) {                                             \
      int rb = wn * 128 + j * 16 + (lane & 15);                               \
      int cb = (BUF) * 2048 + 1024 + rb * 4 + (kc ^ ((rb >> 1) & 3));         \
      bh##S[j] = L[cb];                                                       \
    }                                                                         \
  } while (0)

#define MFMAF(S)                                                              \
  do {                                                                        \
    __builtin_amdgcn_s_setprio(1);                                            \
    _Pragma("unroll")                                                         \
    for (int i = 0; i < 4; ++i)                                               \
      _Pragma("unroll")                                                       \
      for (int j = 0; j < 8; ++j) {                                           \
        acc[i][j] = __builtin_amdgcn_mfma_f32_16x16x32_bf16(ah##S[i], bh##S[j], acc[i][j], 0, 0, 0); \
        acc[i][j] = __builtin_amdgcn_mfma_f32_16x16x32_bf16(al##S[i], bh##S[j], acc[i][j], 0, 0, 0); \
      }                                                                       \
    __builtin_amdgcn_s_setprio(0);                                            \
  } while (0)

// iter ks: drain own prev reads (WAR guard), tile ks+1 landed (tile ks+2's 8
// loads may remain in flight), sync, stage ks+3 into buf ks%3, read frags for
// ks+1, MFMA frags ks.
#define ITER(KS, SB, RB, RS, MS)                                              \
  do {                                                                        \
    asm volatile("s_waitcnt lgkmcnt(0)" ::: "memory");                        \
    asm volatile("s_waitcnt vmcnt(8)" ::: "memory");                          \
    __builtin_amdgcn_s_barrier();                                             \
    STAGE(SB, (KS) + 3);                                                      \
    READF(RS, RB);                                                            \
    MFMAF(MS);                                                                \
  } while (0)

  STAGE(0, 0);
  STAGE(1, 1);
  STAGE(2, 2);                          // 24 loads in flight
  asm volatile("s_waitcnt vmcnt(16)" ::: "memory");   // tile 0 landed
  __builtin_amdgcn_s_barrier();
  READF(A, 0);                          // frags for ks=0

  #pragma unroll 1
  for (int r6 = 0; r6 < 24; r6 += 6) {
    ITER(r6 + 0, 0, 1, B, A);
    ITER(r6 + 1, 1, 2, A, B);
    ITER(r6 + 2, 2, 0, B, A);
    ITER(r6 + 3, 0, 1, A, B);
    ITER(r6 + 4, 1, 2, B, A);
    ITER(r6 + 5, 2, 0, A, B);
  }
  ITER(24, 0, 1, B, A);
  ITER(25, 1, 2, A, B);
  ITER(26, 2, 0, B, A);
  ITER(27, 0, 1, A, B);                 // stages tile 30 -> buf 0
  ITER(28, 1, 2, B, A);                 // stages tile 31 -> buf 1
  // ks = 29: tiles 30,31 in flight; vmcnt(8) -> 30 landed
  asm volatile("s_waitcnt lgkmcnt(0)" ::: "memory");
  asm volatile("s_waitcnt vmcnt(8)" ::: "memory");
  __builtin_amdgcn_s_barrier();
  READF(A, 0);                          // frags for 30 (buf 0)
  MFMAF(B);                             // ks=29
  // ks = 30: need tile 31
  asm volatile("s_waitcnt lgkmcnt(0)" ::: "memory");
  asm volatile("s_waitcnt vmcnt(0)" ::: "memory");
  __builtin_amdgcn_s_barrier();
  READF(B, 1);                          // frags for 31 (buf 1)
  MFMAF(A);                             // ks=30
  MFMAF(B);                             // ks=31
  __builtin_amdgcn_s_barrier();         // all LDS reads done -> smem reusable

#undef ITER
#undef MFMAF
#undef READF
#undef STAGE

  // ------------------------- fused epilogue --------------------------------
  const int bm = mt * 128, bn = nt * 64;
  const int nl = (tid & 15) * 4;      // 4 n-cols per thread
  const int ml = (tid >> 4) * 8;      // 8 m-rows per thread

  float* pre = (float*)smem;          // [2][128][68] fp32 = 69632 B

  // phase 1: gates 0 (i), 1 (f)  — held by wn==0 waves (j>>2 = gate)
  if (wn == 0) {
    #pragma unroll
    for (int i = 0; i < 4; ++i)
      #pragma unroll
      for (int j = 0; j < 8; ++j) {
        int slot = j >> 2;
        int c = (j & 3) * 16 + (lane & 15);
        #pragma unroll
        for (int r = 0; r < 4; ++r) {
          int m = wm * 64 + i * 16 + ((lane >> 4) * 4) + r;
          pre[(slot * 128 + m) * 68 + c] = acc[i][j][r];
        }
      }
  }
  asm volatile("s_waitcnt lgkmcnt(0)" ::: "memory");
  __builtin_amdgcn_s_barrier();

  f32x4 iv[8], fv[8];
  #pragma unroll
  for (int r8 = 0; r8 < 8; ++r8) {
    int m = ml + r8;
    f32x4 pi = *(const f32x4*)&pre[(0 * 128 + m) * 68 + nl];
    f32x4 pf = *(const f32x4*)&pre[(1 * 128 + m) * 68 + nl];
    const float* xr = xg + (size_t)(bm + m) * G_SZ + bn + nl;
    f32x4 x0 = *(const f32x4*)xr;
    f32x4 x1 = *(const f32x4*)(xr + H_SZ);
    #pragma unroll
    for (int j = 0; j < 4; ++j) {
      iv[r8][j] = sigmoid_f(pi[j] + x0[j]);
      fv[r8][j] = sigmoid_f(pf[j] + x1[j]);
    }
  }
  __builtin_amdgcn_s_barrier();       // phase-1 reads done before overwrite

  // phase 2: gates 2 (g), 3 (o)  — held by wn==1 waves
  if (wn == 1) {
    #pragma unroll
    for (int i = 0; i < 4; ++i)
      #pragma unroll
      for (int j = 0; j < 8; ++j) {
        int slot = j >> 2;
        int c = (j & 3) * 16 + (lane & 15);
        #pragma unroll
        for (int r = 0; r < 4; ++r) {
          int m = wm * 64 + i * 16 + ((lane >> 4) * 4) + r;
          pre[(slot * 128 + m) * 68 + c] = acc[i][j][r];
        }
      }
  }
  asm volatile("s_waitcnt lgkmcnt(0)" ::: "memory");
  __builtin_amdgcn_s_barrier();

  __bf16* ph = (__bf16*)hnh;
  __bf16* pl = (__bf16*)hnl;
  #pragma unroll
  for (int r8 = 0; r8 < 8; ++r8) {
    int m = ml + r8;
    int mg = bm + m;
    f32x4 pg = *(const f32x4*)&pre[(0 * 128 + m) * 68 + nl];
    f32x4 po = *(const f32x4*)&pre[(1 * 128 + m) * 68 + nl];
    const float* xr = xg + (size_t)mg * G_SZ + bn + nl;
    f32x4 x2 = *(const f32x4*)(xr + 2 * H_SZ);
    f32x4 x3 = *(const f32x4*)(xr + 3 * H_SZ);
    f32x4 cvv;
    if (first) cvv = (f32x4){INIT_ST, INIT_ST, INIT_ST, INIT_ST};
    else       cvv = *(const f32x4*)(cst + (size_t)mg * H_SZ + bn + nl);
    f32x4 cnew, hv;
    #pragma unroll
    for (int j = 0; j < 4; ++j) {
      float gv = tanh_f(pg[j] + x2[j]);
      float ov = sigmoid_f(po[j] + x3[j]);
      cnew[j] = fv[r8][j] * cvv[j] + iv[r8][j] * gv;
      hv[j]   = ov * tanh_f(cnew[j]);
    }
    *(f32x4*)(cst  + (size_t)mg * H_SZ + bn + nl) = cnew;
    *(f32x4*)(hout + (size_t)mg * H_SZ + bn + nl) = hv;

    // split for next step's A layout ([mt64][ks][256], swizzle v2)
    int nglob = bn + nl;
    int ks2 = nglob >> 5;
    int kc2 = (nglob >> 3) & 3;
    int eb  = nglob & 7;                 // 0 or 4
    int r64 = m & 63;
    int mt64 = 2 * mt + (m >> 6);
    int s2  = r64 * 4 + (kc2 ^ ((r64 >> 1) & 3));
    size_t ci = (((size_t)mt64 * 32 + ks2) * 256 + s2) * 8 + eb;
    union { __bf16 b[4]; uint2 u; } uh, ul;
    #pragma unroll
    for (int j = 0; j < 4; ++j) {
      __bf16 hb = (__bf16)hv[j];
      uh.b[j] = hb;
      ul.b[j] = (__bf16)(hv[j] - (float)hb);
    }
    *(uint2*)(ph + ci) = uh.u;
    *(uint2*)(pl + ci) = ul.u;
  }
}

extern "C" void kernel_launch(void* const* d_in, const int* in_sizes, int n_in,
                              void* d_out, int out_size, void* d_ws, size_t ws_size,
                              hipStream_t stream)
{
  const float* x   = (const float*)d_in[0];
  const float* Wih = (const float*)d_in[1];
  const float* Whh = (const float*)d_in[2];
  const float* bih = (const float*)d_in[3];
  const float* bhh = (const float*)d_in[4];
  float* out = (float*)d_out;

  // ws layout (64 MB total):
  float*  xg  = (float*)d_ws;                              // 32 MB
  float*  cst = xg + (size_t)B_SZ * G_SZ;                  //  8 MB
  bf16x8* Wh  = (bf16x8*)(cst + (size_t)B_SZ * H_SZ);      //  8 MB
  bf16x8* hAh = Wh + 524288;                               //  4 MB
  bf16x8* hAl = hAh + 262144;                              //  4 MB
  bf16x8* hBh = hAl + 262144;                              //  4 MB
  bf16x8* hBl = hBh + 262144;                              //  4 MB

  repack_whh<<<2048, 256, 0, stream>>>(Whh, Wh);
  init_h0<<<1024, 256, 0, stream>>>(hAh, hAl);
  xg_gemm<<<dim3(G_SZ / 128, B_SZ / 128), 256, 0, stream>>>(x, Wih, bih, bhh, xg);

  for (int t = 0; t < T_STEPS; ++t) {
    const bf16x8* rh = (t & 1) ? hBh : hAh;
    const bf16x8* rl = (t & 1) ? hBl : hAl;
    bf16x8* wh = (t & 1) ? hAh : hBh;
    bf16x8* wl = (t & 1) ? hAl : hBl;
    lstm_step<<<256, 256, 0, stream>>>(rh, rl, Wh, xg, cst,
                                       out + (size_t)t * B_SZ * H_SZ, wh, wl,
                                       t == 0 ? 1 : 0);
  }
}